// Round 8
// baseline (329.894 us; speedup 1.0000x reference)
//
#include <hip/hip_runtime.h>

// GCN 3-layer forward on gfx950.
// Round 20: overlap + pipelined gather.
//  - R19 counters: fill 42us WRITE 48.6MB (write-merge theory FAILED - same-line
//    stores temporally scattered -> full 64B/store amplification; sorting too
//    costly). Fill is only 23% HBM / 5.5% VALU -> hide independent GEMM1 inside
//    it: gemm1 blocks fused into fill kernel's grid (W-conv moved to cnt_k so
//    W1h is ready; gemm1 depends only on x,W1h).
//  - gather (42us, occ 64%, VALU 37%): persistent grid-stride waves (2048
//    blocks = exactly resident), next-row rowstart issued before current row's
//    edge loop, edge loop's last prefetch slot fetches next row's first pairs
//    batch -> serial chain ~3.5 RT/row -> ~2 RT/row. Wave count and VGPR
//    occupancy preserved (P/Q reuse, single accumulator pair; R18 lesson).
// CSR build (8-pad incl self edge), partitioned fill, GEMM body unchanged.

#define IN_CH 128

typedef __attribute__((ext_vector_type(8))) short bf16x8;
typedef __attribute__((ext_vector_type(4))) float f32x4;

__device__ inline unsigned short f2bf_rne(float f) {
    unsigned u = __float_as_uint(f);
    unsigned r = (u + 0x7FFFu + ((u >> 16) & 1u)) >> 16;
    return (unsigned short)r;
}
__device__ inline float bf2f(unsigned short h) {
    return __uint_as_float(((unsigned)h) << 16);
}
__device__ inline float bf2f_lo(unsigned m) {
    return __uint_as_float(m << 16);
}
__device__ inline float bf2f_hi(unsigned m) {
    return __uint_as_float(m & 0xffff0000u);
}

// ---------------- degree count + W conversion (independent work fused) -----
__device__ inline void convw_one(const float* W, unsigned short* hi, int FOUT, int id) {
    int n = id >> 7, k = id & 127;
    hi[id] = f2bf_rne(W[k * FOUT + n]);
}

__global__ __launch_bounds__(256) void cntconv_k(
    const int* __restrict__ dst, int* __restrict__ cnt, int E, int cntBlocks,
    const float* __restrict__ W1, const float* __restrict__ W2,
    const float* __restrict__ W3,
    unsigned short* __restrict__ W1h, unsigned short* __restrict__ W2h,
    unsigned short* __restrict__ W3h) {
    if ((int)blockIdx.x < cntBlocks) {
        int e = blockIdx.x * 256 + threadIdx.x;
        if (e < E) atomicAdd(&cnt[dst[e]], 1);
    } else {
        int id = (blockIdx.x - cntBlocks) * 256 + threadIdx.x;
        if (id < 16384) convw_one(W1, W1h, 128, id);
        else if (id < 32768) convw_one(W2, W2h, 128, id - 16384);
        else if (id < 40960) convw_one(W3, W3h, 64, id - 32768);
    }
}

// ---------------- scan stage 1 on PADDED counts (+ dinv from real) --------
// padded count includes the self edge: (cnt+1 rounded up to 8)
__global__ __launch_bounds__(256) void scan1_k(const int* __restrict__ cnt,
                                               int* __restrict__ bsum,
                                               float* __restrict__ dinv, int N) {
    __shared__ int s[256];
    int tid = threadIdx.x;
    int i = blockIdx.x * 256 + tid;
    int vr = (i < N) ? cnt[i] : 0;
    if (i < N) dinv[i] = rsqrtf((float)vr + 1.0f);
    s[tid] = (i < N) ? ((vr + 8) & ~7) : 0;  // self edge + pad to 8
    __syncthreads();
    for (int off = 128; off > 0; off >>= 1) {
        if (tid < off) s[tid] += s[tid + off];
        __syncthreads();
    }
    if (tid == 0) bsum[blockIdx.x] = s[0];
}

__global__ __launch_bounds__(512) void scan2_k(int* __restrict__ bsum, int nb) {
    __shared__ int s[512];
    __shared__ int carry_s;
    int tid = threadIdx.x;
    if (tid == 0) carry_s = 0;
    __syncthreads();
    for (int base = 0; base < nb; base += 512) {
        int c = carry_s;
        int i = base + tid;
        int v = (i < nb) ? bsum[i] : 0;
        s[tid] = v;
        __syncthreads();
        for (int off = 1; off < 512; off <<= 1) {
            int t = (tid >= off) ? s[tid - off] : 0;
            __syncthreads();
            s[tid] += t;
            __syncthreads();
        }
        if (i < nb) bsum[i] = s[tid] - v + c;
        __syncthreads();
        if (tid == 0) carry_s = c + s[511];
        __syncthreads();
    }
}

// scan3: padded exclusive scan -> rowstart[N+1] (preserved) + cur[N] (cursor)
__global__ __launch_bounds__(256) void scan3_k(const int* __restrict__ cnt,
                                               const int* __restrict__ bsum,
                                               int* __restrict__ rowstart,
                                               int* __restrict__ cur, int N) {
    __shared__ int s[256];
    int tid = threadIdx.x;
    int i = blockIdx.x * 256 + tid;
    int v = (i < N) ? ((cnt[i] + 8) & ~7) : 0;
    s[tid] = v;
    __syncthreads();
    for (int off = 1; off < 256; off <<= 1) {
        int t = (tid >= off) ? s[tid - off] : 0;
        __syncthreads();
        s[tid] += t;
        __syncthreads();
    }
    if (i < N) {
        int st = s[tid] - v + bsum[blockIdx.x];
        rowstart[i] = st;
        cur[i] = st;
        if (i == N - 1) rowstart[N] = st + v;
    }
}

// ---------------- MFMA GEMM body: T[N][FOUT] = A[N][128] @ W[128][FOUT] ----
__device__ inline bf16x8 cvt8(const float* __restrict__ p) {
    float4 v0 = *(const float4*)p;
    float4 v1 = *(const float4*)(p + 4);
    bf16x8 h;
    h[0] = (short)f2bf_rne(v0.x); h[1] = (short)f2bf_rne(v0.y);
    h[2] = (short)f2bf_rne(v0.z); h[3] = (short)f2bf_rne(v0.w);
    h[4] = (short)f2bf_rne(v1.x); h[5] = (short)f2bf_rne(v1.y);
    h[6] = (short)f2bf_rne(v1.z); h[7] = (short)f2bf_rne(v1.w);
    return h;
}

template <int FOUT, bool AF32>
__device__ inline void gemm_body(int bid, const float* __restrict__ Af,
                                 const unsigned short* __restrict__ Ahi,
                                 const unsigned short* __restrict__ Bhi,
                                 unsigned short* __restrict__ Thi, int N,
                                 unsigned short* smem) {
    constexpr int NCT = FOUT / 16;
    constexpr int BSTRIDE = 136;
    constexpr int CSTRIDE = FOUT + 8;

    const int tid = threadIdx.x;
    const int wv = tid >> 6, lane = tid & 63;
    const int quad = lane >> 4, l16 = lane & 15;
    const int row0 = bid * 64 + wv * 16;

#pragma unroll
    for (int it = 0; it < FOUT / 16; ++it) {
        int i = it * 256 + tid;
        int r = i >> 4, c = (i & 15) * 8;
        *(bf16x8*)(&smem[r * BSTRIDE + c]) = *(const bf16x8*)(Bhi + (size_t)r * 128 + c);
    }
    __syncthreads();

    f32x4 acc[NCT];
#pragma unroll
    for (int ct = 0; ct < NCT; ++ct)
        acc[ct] = (f32x4){0.f, 0.f, 0.f, 0.f};

    const int ra = AF32 ? min(row0 + l16, N - 1) : (row0 + l16);

#pragma unroll
    for (int ks = 0; ks < 4; ++ks) {
        const int ko = ks * 32 + quad * 8;
        bf16x8 ah;
        if (AF32) {
            ah = cvt8(Af + (size_t)ra * 128 + ko);
        } else {
            ah = *(const bf16x8*)(Ahi + (size_t)ra * 128 + ko);
        }
#pragma unroll
        for (int ct = 0; ct < NCT; ++ct) {
            bf16x8 bh = *(const bf16x8*)(&smem[(ct * 16 + l16) * BSTRIDE + ko]);
            acc[ct] = __builtin_amdgcn_mfma_f32_16x16x32_bf16(ah, bh, acc[ct], 0, 0, 0);
        }
    }

    __syncthreads();
    const int lrow = wv * 16 + quad * 4;
#pragma unroll
    for (int ct = 0; ct < NCT; ++ct) {
        const int col = ct * 16 + l16;
#pragma unroll
        for (int r = 0; r < 4; ++r)
            smem[(lrow + r) * CSTRIDE + col] = f2bf_rne(acc[ct][r]);
    }
    __syncthreads();
    constexpr int CH = FOUT / 8;
#pragma unroll
    for (int i = 0; i < 64 * CH / 256; ++i) {
        int ci = i * 256 + tid;
        int r = ci / CH, c = (ci % CH) * 8;
        int grow = bid * 64 + r;
        if (grow < N)
            *(uint4*)(Thi + (size_t)grow * FOUT + c) = *(const uint4*)&smem[r * CSTRIDE + c];
    }
}

template <int FOUT, bool AF32>
__global__ __launch_bounds__(256) void mfma_gemm(const float* __restrict__ Af,
                                                 const unsigned short* __restrict__ Ahi,
                                                 const unsigned short* __restrict__ Bhi,
                                                 unsigned short* __restrict__ Thi,
                                                 int N) {
    constexpr int BU = FOUT * 136;
    constexpr int CU2 = 64 * (FOUT + 8);
    constexpr int SMEMU = (BU > CU2) ? BU : CU2;
    __shared__ unsigned short smem[SMEMU];
    gemm_body<FOUT, AF32>(blockIdx.x, Af, Ahi, Bhi, Thi, N, smem);
}

// ---------------- fused fill (CSR pairs + self edges) + GEMM1 --------------
// Block layout: [0,gemmBlocks) = gemm1 (x @ W1h -> Thi, independent of CSR);
// [gemmBlocks, +fillBlocks) = partitioned edge fill; then self-edge blocks.
__global__ __launch_bounds__(256) void fillgemm_k(
    const int* __restrict__ src, const int* __restrict__ dst,
    const float* __restrict__ dinv, int* __restrict__ cur,
    int2* __restrict__ pairs, int E, int N, int gemmBlocks, int fillBlocks,
    int rangeSz,
    const float* __restrict__ x, const unsigned short* __restrict__ W1h,
    unsigned short* __restrict__ Thi) {
    __shared__ unsigned short smem[128 * 136];
    if ((int)blockIdx.x < gemmBlocks) {
        gemm_body<128, true>(blockIdx.x, x, nullptr, W1h, Thi, N, smem);
        return;
    }
    const int fb = blockIdx.x - gemmBlocks;
    if (fb < fillBlocks) {
        const int range = fb & 7;  // blockIdx offset by const -> still XCD-bijective
        const int lo = range * rangeSz;
        const int hi = lo + rangeSz;
        const int e0 = (fb >> 3) * 1024 + threadIdx.x * 4;
        if (e0 >= E) return;
        int s[4], d[4];
        if (e0 + 4 <= E) {
            int4 s4 = *(const int4*)(src + e0);
            int4 d4 = *(const int4*)(dst + e0);
            s[0] = s4.x; s[1] = s4.y; s[2] = s4.z; s[3] = s4.w;
            d[0] = d4.x; d[1] = d4.y; d[2] = d4.z; d[3] = d4.w;
        } else {
#pragma unroll
            for (int k = 0; k < 4; ++k) {
                s[k] = (e0 + k < E) ? src[e0 + k] : 0;
                d[k] = (e0 + k < E) ? dst[e0 + k] : -1;  // never in range
            }
        }
#pragma unroll
        for (int k = 0; k < 4; ++k) {
            if (d[k] >= lo && d[k] < hi) {
                float nrm = dinv[s[k]] * dinv[d[k]];
                int pos = atomicAdd(&cur[d[k]], 1);
                pairs[pos] = make_int2(s[k] * 256, __float_as_int(nrm));  // byte offset
            }
        }
    } else {
        // self edges: one per node, norm = dinv^2
        int i = (fb - fillBlocks) * 256 + threadIdx.x;
        if (i < N) {
            float di = dinv[i];
            int pos = atomicAdd(&cur[i], 1);
            pairs[pos] = make_int2(i * 256, __float_as_int(di * di));
        }
    }
}

// ---------------- gather: persistent waves, row-pipelined, 8-unrolled ------
// res[row] = b + sum_e norm_e * Thi@off_e  (self edge included in pairs)
// Rows padded to 8-multiples (>=1 iter/row). Wave walks rows gw, gw+GW, ...
// Next row's rowstart issued before current row's edge loop; edge loop's
// last prefetch slot loads the next row's first pairs batch.
struct Pairs4 { int4 p0, p1, p2, p3; };

__device__ inline Pairs4 ldpairs(const int2* __restrict__ pairs, int j) {
    Pairs4 r;
    r.p0 = *(const int4*)(pairs + j);
    r.p1 = *(const int4*)(pairs + j + 2);
    r.p2 = *(const int4*)(pairs + j + 4);
    r.p3 = *(const int4*)(pairs + j + 6);
    return r;
}

__device__ inline void ldrows128(const char* __restrict__ tbase, int laneB,
                                 const Pairs4& P, unsigned m[8]) {
    m[0] = *(const unsigned*)(tbase + (unsigned)P.p0.x + laneB);
    m[1] = *(const unsigned*)(tbase + (unsigned)P.p0.z + laneB);
    m[2] = *(const unsigned*)(tbase + (unsigned)P.p1.x + laneB);
    m[3] = *(const unsigned*)(tbase + (unsigned)P.p1.z + laneB);
    m[4] = *(const unsigned*)(tbase + (unsigned)P.p2.x + laneB);
    m[5] = *(const unsigned*)(tbase + (unsigned)P.p2.z + laneB);
    m[6] = *(const unsigned*)(tbase + (unsigned)P.p3.x + laneB);
    m[7] = *(const unsigned*)(tbase + (unsigned)P.p3.z + laneB);
}

__device__ inline void fma8_128(const Pairs4& P, const unsigned m[8],
                                float& ax, float& ay) {
    float n0 = __int_as_float(P.p0.y), n1 = __int_as_float(P.p0.w);
    float n2 = __int_as_float(P.p1.y), n3 = __int_as_float(P.p1.w);
    float n4 = __int_as_float(P.p2.y), n5 = __int_as_float(P.p2.w);
    float n6 = __int_as_float(P.p3.y), n7 = __int_as_float(P.p3.w);
    ax += n0 * bf2f_lo(m[0]); ay += n0 * bf2f_hi(m[0]);
    ax += n1 * bf2f_lo(m[1]); ay += n1 * bf2f_hi(m[1]);
    ax += n2 * bf2f_lo(m[2]); ay += n2 * bf2f_hi(m[2]);
    ax += n3 * bf2f_lo(m[3]); ay += n3 * bf2f_hi(m[3]);
    ax += n4 * bf2f_lo(m[4]); ay += n4 * bf2f_hi(m[4]);
    ax += n5 * bf2f_lo(m[5]); ay += n5 * bf2f_hi(m[5]);
    ax += n6 * bf2f_lo(m[6]); ay += n6 * bf2f_hi(m[6]);
    ax += n7 * bf2f_lo(m[7]); ay += n7 * bf2f_hi(m[7]);
}

__device__ inline void ldrows64(const char* __restrict__ tbase, int laneB,
                                const Pairs4& P, float m[8]) {
    m[0] = bf2f(*(const unsigned short*)(tbase + ((unsigned)P.p0.x >> 1) + laneB));
    m[1] = bf2f(*(const unsigned short*)(tbase + ((unsigned)P.p0.z >> 1) + laneB));
    m[2] = bf2f(*(const unsigned short*)(tbase + ((unsigned)P.p1.x >> 1) + laneB));
    m[3] = bf2f(*(const unsigned short*)(tbase + ((unsigned)P.p1.z >> 1) + laneB));
    m[4] = bf2f(*(const unsigned short*)(tbase + ((unsigned)P.p2.x >> 1) + laneB));
    m[5] = bf2f(*(const unsigned short*)(tbase + ((unsigned)P.p2.z >> 1) + laneB));
    m[6] = bf2f(*(const unsigned short*)(tbase + ((unsigned)P.p3.x >> 1) + laneB));
    m[7] = bf2f(*(const unsigned short*)(tbase + ((unsigned)P.p3.z >> 1) + laneB));
}

__device__ inline void fma8_64(const Pairs4& P, const float m[8], float& acc) {
    acc += __int_as_float(P.p0.y) * m[0] + __int_as_float(P.p0.w) * m[1] +
           __int_as_float(P.p1.y) * m[2] + __int_as_float(P.p1.w) * m[3] +
           __int_as_float(P.p2.y) * m[4] + __int_as_float(P.p2.w) * m[5] +
           __int_as_float(P.p3.y) * m[6] + __int_as_float(P.p3.w) * m[7];
}

template <int FOUT, bool SPLIT>
__global__ __launch_bounds__(256) void gather_k(const int* __restrict__ rowstart,
                                                const int2* __restrict__ pairs,
                                                const unsigned short* __restrict__ Thi,
                                                const float* __restrict__ bias,
                                                float* __restrict__ out,
                                                unsigned short* __restrict__ outHi,
                                                int N) {
    const int wave = threadIdx.x >> 6;
    const int lane = threadIdx.x & 63;
    const int GW = gridDim.x * 4;
    int row = blockIdx.x * 4 + wave;
    if (row >= N) return;
    const char* tbase = (const char*)Thi;

    int sC = rowstart[row];
    int eC = rowstart[row + 1];
    Pairs4 P = ldpairs(pairs, sC);

    if (FOUT == 128) {
        const int laneB = lane * 4;
        const float2 bb = *(const float2*)(bias + lane * 2);
        for (;;) {
            const int nrow = row + GW;
            const bool hasN = nrow < N;
            int sN = sC, eN = eC;
            if (hasN) { sN = rowstart[nrow]; eN = rowstart[nrow + 1]; }
            float ax = bb.x, ay = bb.y;
            int j = sC;
            for (;;) {
                unsigned m[8];
                ldrows128(tbase, laneB, P, m);
                j += 8;
                const bool more = j < eC;
                const int pj = more ? j : sN;  // next batch or next row's first
                Pairs4 Q = ldpairs(pairs, pj);
                fma8_128(P, m, ax, ay);
                P = Q;
                if (!more) break;
            }
            if (SPLIT) {
                ushort2 h;
                h.x = f2bf_rne(fmaxf(ax, 0.f));
                h.y = f2bf_rne(fmaxf(ay, 0.f));
                *(ushort2*)(outHi + (size_t)row * 128 + lane * 2) = h;
            } else {
                float2 o; o.x = ax; o.y = ay;
                *(float2*)(out + (size_t)row * 128 + lane * 2) = o;
            }
            if (!hasN) break;
            row = nrow; sC = sN; eC = eN;
        }
    } else {  // FOUT == 64: rows are 128B; byte offset = off>>1
        const int laneB = lane * 2;
        const float bb = bias[lane];
        for (;;) {
            const int nrow = row + GW;
            const bool hasN = nrow < N;
            int sN = sC, eN = eC;
            if (hasN) { sN = rowstart[nrow]; eN = rowstart[nrow + 1]; }
            float acc = bb;
            int j = sC;
            for (;;) {
                float m[8];
                ldrows64(tbase, laneB, P, m);
                j += 8;
                const bool more = j < eC;
                const int pj = more ? j : sN;
                Pairs4 Q = ldpairs(pairs, pj);
                fma8_64(P, m, acc);
                P = Q;
                if (!more) break;
            }
            out[(size_t)row * FOUT + lane] = acc;
            if (!hasN) break;
            row = nrow; sC = sN; eC = eN;
        }
    }
}

extern "C" void kernel_launch(void* const* d_in, const int* in_sizes, int n_in,
                              void* d_out, int out_size, void* d_ws, size_t ws_size,
                              hipStream_t stream) {
    const float* x  = (const float*)d_in[0];
    const int* eidx = (const int*)d_in[1];
    const float* W1 = (const float*)d_in[2];
    const float* b1 = (const float*)d_in[3];
    const float* W2 = (const float*)d_in[4];
    const float* b2 = (const float*)d_in[5];
    const float* W3 = (const float*)d_in[6];
    const float* b3 = (const float*)d_in[7];
    float* out = (float*)d_out;

    const int N = in_sizes[0] / IN_CH;
    const int E = in_sizes[1] / 2;
    const int* src = eidx;
    const int* dst = eidx + E;
    const int Npad = ((N + 127) / 128) * 128;
    const int nb = (N + 255) / 256;
    const int Emax = E + 8 * N + 24;  // self edges + 8-pad + prefetch slack

    auto align = [](size_t v) { return (v + 255) / 256 * 256; };
    char* p = (char*)d_ws;
    int* cnt = (int*)p;            p += align((size_t)N * 4);
    int* rowstart = (int*)p;       p += align((size_t)(N + 1) * 4);
    int* cur = (int*)p;            p += align((size_t)N * 4);
    int* bsum = (int*)p;           p += align((size_t)nb * 4);
    float* dinv = (float*)p;       p += align((size_t)N * 4);
    int2* pairs = (int2*)p;        p += align((size_t)Emax * 8);
    unsigned short* Ahi = (unsigned short*)p;  p += align((size_t)Npad * 128 * 2);
    unsigned short* Thi = (unsigned short*)p;  p += align((size_t)Npad * 128 * 2);
    unsigned short* W1h = (unsigned short*)p;  p += align(128 * 128 * 2);
    unsigned short* W2h = (unsigned short*)p;  p += align(128 * 128 * 2);
    unsigned short* W3h = (unsigned short*)p;

    // ---- CSR build (once; reused by all 3 layers) ----
    hipMemsetAsync(cnt, 0, (size_t)N * 4, stream);
    hipMemsetAsync(pairs, 0, (size_t)Emax * 8, stream);  // pad edges = (0,0)
    const int cntBlocks = (E + 255) / 256;
    cntconv_k<<<cntBlocks + 160, 256, 0, stream>>>(dst, cnt, E, cntBlocks,
                                                   W1, W2, W3, W1h, W2h, W3h);
    scan1_k<<<nb, 256, 0, stream>>>(cnt, bsum, dinv, N);
    scan2_k<<<1, 512, 0, stream>>>(bsum, nb);
    scan3_k<<<nb, 256, 0, stream>>>(cnt, bsum, rowstart, cur, N);

    // fused: gemm1 (independent) + partitioned edge fill + self edges
    const int gemm_blocks = (N + 63) / 64;
    const int chunks = (E + 1023) / 1024;
    const int fillBlocks = chunks * 8;
    const int selfBlocks = (N + 255) / 256;
    const int rangeSz = (N + 7) / 8;
    fillgemm_k<<<gemm_blocks + fillBlocks + selfBlocks, 256, 0, stream>>>(
        src, dst, dinv, cur, pairs, E, N, gemm_blocks, fillBlocks, rangeSz,
        x, W1h, Thi);

    const int gather_blocks = min(2048, (N + 3) / 4);

    // Layer 1 aggregation
    gather_k<128, true><<<gather_blocks, 256, 0, stream>>>(rowstart, pairs, Thi,
                                                           b1, nullptr, Ahi, N);
    // Layer 2
    mfma_gemm<128, false><<<gemm_blocks, 256, 0, stream>>>(nullptr, Ahi, W2h, Thi, N);
    gather_k<128, true><<<gather_blocks, 256, 0, stream>>>(rowstart, pairs, Thi,
                                                           b2, nullptr, Ahi, N);
    // Layer 3
    mfma_gemm<64, false><<<gemm_blocks, 256, 0, stream>>>(nullptr, Ahi, W3h, Thi, N);
    gather_k<64, false><<<gather_blocks, 256, 0, stream>>>(rowstart, pairs, Thi,
                                                           b3, out, nullptr, N);
}